// Round 13
// baseline (190.432 us; speedup 1.0000x reference)
//
#include <hip/hip_runtime.h>

#define BINS 10
#define TPB  256
#define NB_MAX 2048
#define FTPB 1024   // finalize block size
#define KPACK 16384.0f
#define LN2f   0.69314718055994531f
#define LOG2Ef 1.44269504088896f

// ---------------- ablation probes (round 13) ----------------
// Same geometry as the hist kernel (grid 2048 x 256, 5 quads/thread at the
// bench shape), run 4 passes each so they show up in the top-5 rocprof rows.
// Pass index is XOR'd into the quad index (stays within a 64B group ->
// coalescing preserved) to prevent cross-pass load CSE/hoisting.

__global__ __launch_bounds__(TPB, 4) void probe_stream_x4(
    const float4* __restrict__ pred4,
    const int4*   __restrict__ tgt4,
    const int4*   __restrict__ lw4,
    float* __restrict__ out, int n4)
{
    const int tid    = threadIdx.x;
    const int stride = gridDim.x * TPB;
    const int base   = blockIdx.x * TPB + tid;
    const int full   = n4 / stride;

    float s = 0.f;
    int   si = 0;
    for (int pass = 0; pass < 4; ++pass) {
        for (int k = 0; k < full; ++k) {
            int i = (base + k * stride) ^ pass;   // defeat cross-pass CSE
            if (i < n4) {
                float4 a = pred4[i];
                int4   b = tgt4[i];
                int4   c = lw4[i];
                s  += a.x + a.y + a.z + a.w;
                si += b.x + b.y + b.z + b.w + c.x + c.y + c.z + c.w;
            }
        }
    }
    s += (float)si;
#pragma unroll
    for (int off = 1; off <= 32; off <<= 1) s += __shfl_xor(s, off, 64);
    if ((tid & 63) == 0)
        out[blockIdx.x * 4 + (tid >> 6)] = s;   // overwritten by hist later
}

__global__ __launch_bounds__(TPB, 4) void probe_proc_x4(
    const float4* __restrict__ pred4,
    const int4*   __restrict__ tgt4,
    const int4*   __restrict__ lw4,
    float* __restrict__ out, int n4)
{
    const int tid    = threadIdx.x;
    const int stride = gridDim.x * TPB;
    const int base   = blockIdx.x * TPB + tid;
    const int full   = n4 / stride;

    float A[BINS];
#pragma unroll
    for (int b = 0; b < BINS; ++b) A[b] = 0.f;

    const float Q[9] = {-2.19722458f, -1.38629436f, -0.84729786f,
                        -0.40546511f,  0.0f,         0.40546511f,
                         0.84729786f,  1.38629436f,  2.19722458f};

    auto proc = [&](float p, int t, int w) {
        float q    = __int_as_float(__float_as_int(p) ^ (int)((unsigned)t << 31));
        float e    = __builtin_amdgcn_exp2f(fabsf(q) * -LOG2Ef);
        float d    = 1.f + e;
        float bce2 = fmaf(fmaxf(q, 0.f), LOG2Ef, __builtin_amdgcn_logf(d));
        float v    = (w > 0) ? (bce2 + KPACK) : 0.f;
        A[0] += v;
#pragma unroll
        for (int k = 0; k < 9; ++k)
            A[k + 1] += (q >= Q[k]) ? v : 0.f;
    };

    for (int pass = 0; pass < 4; ++pass) {
        for (int k = 0; k < full; ++k) {
            int i = (base + k * stride) ^ pass;
            if (i < n4) {
                float4 p = pred4[i];
                int4   t = tgt4[i];
                int4   w = lw4[i];
                proc(p.x, t.x, w.x); proc(p.y, t.y, w.y);
                proc(p.z, t.z, w.z); proc(p.w, t.w, w.w);
            }
        }
    }
    float s = 0.f;
#pragma unroll
    for (int b = 0; b < BINS; ++b) s += A[b] * (float)(b + 1);
#pragma unroll
    for (int off = 1; off <= 32; off <<= 1) s += __shfl_xor(s, off, 64);
    if ((tid & 63) == 0)
        out[blockIdx.x * 4 + (tid >> 6)] = s;   // overwritten by hist later
}

// ---------------- real kernels (unchanged from round 12) ----------------

// Fire-and-forget global->LDS load, 16 bytes, per-thread slot.
template <typename T>
__device__ __forceinline__ void gload16(const T* g, T* l) {
    __builtin_amdgcn_global_load_lds(
        (const __attribute__((address_space(1))) void*)g,
        (__attribute__((address_space(3))) void*)l, 16, 0, 0);
}

__global__ __launch_bounds__(TPB, 4) void ghmc_hist_kernel(
    const float4* __restrict__ pred4,
    const int4*   __restrict__ tgt4,
    const int4*   __restrict__ lw4,
    float* __restrict__ part,      // [nb][2*BINS]
    int n4, int n)
{
    __shared__ float4 Lp[2][TPB];
    __shared__ int4   Lt[2][TPB];
    __shared__ int4   Lw[2][TPB];
    __shared__ float  red[2 * BINS][16];

    float A[BINS];
#pragma unroll
    for (int b = 0; b < BINS; ++b) A[b] = 0.f;

    const float Q[9] = {-2.19722458f, -1.38629436f, -0.84729786f,
                        -0.40546511f,  0.0f,         0.40546511f,
                         0.84729786f,  1.38629436f,  2.19722458f};

    auto proc = [&](float p, int t, int w) {
        float q    = __int_as_float(__float_as_int(p) ^ (int)((unsigned)t << 31));
        float e    = __builtin_amdgcn_exp2f(fabsf(q) * -LOG2Ef);   // e^-|q|
        float d    = 1.f + e;
        float bce2 = fmaf(fmaxf(q, 0.f), LOG2Ef,
                          __builtin_amdgcn_logf(d));               // softplus/ln2
        float v    = (w > 0) ? (bce2 + KPACK) : 0.f;
        A[0] += v;
#pragma unroll
        for (int k = 0; k < 9; ++k)
            A[k + 1] += (q >= Q[k]) ? v : 0.f;   // bin >= k+1  <=>  q >= Q[k]
    };

    const int tid    = threadIdx.x;
    const int stride = gridDim.x * TPB;
    const int base   = blockIdx.x * TPB + tid;
    const int full   = n4 / stride;

    if (full >= 2) {
        gload16(&pred4[base],          &Lp[0][tid]);
        gload16(&tgt4 [base],          &Lt[0][tid]);
        gload16(&lw4  [base],          &Lw[0][tid]);
        gload16(&pred4[base + stride], &Lp[1][tid]);
        gload16(&tgt4 [base + stride], &Lt[1][tid]);
        gload16(&lw4  [base + stride], &Lw[1][tid]);

        for (int k = 0; k < full - 1; ++k) {
            asm volatile("s_waitcnt vmcnt(3)" ::: "memory");
            __builtin_amdgcn_sched_barrier(0);
            const int b2 = k & 1;
            float4 p = Lp[b2][tid];
            int4   t = Lt[b2][tid];
            int4   w = Lw[b2][tid];
            asm volatile("s_waitcnt lgkmcnt(0)" ::: "memory");
            __builtin_amdgcn_sched_barrier(0);
            if (k + 2 < full) {
                const int j = base + (k + 2) * stride;
                gload16(&pred4[j], &Lp[b2][tid]);
                gload16(&tgt4 [j], &Lt[b2][tid]);
                gload16(&lw4  [j], &Lw[b2][tid]);
            }
            proc(p.x, t.x, w.x); proc(p.y, t.y, w.y);
            proc(p.z, t.z, w.z); proc(p.w, t.w, w.w);
        }
        {
            asm volatile("s_waitcnt vmcnt(0)" ::: "memory");
            __builtin_amdgcn_sched_barrier(0);
            const int b2 = (full - 1) & 1;
            float4 p = Lp[b2][tid];
            int4   t = Lt[b2][tid];
            int4   w = Lw[b2][tid];
            proc(p.x, t.x, w.x); proc(p.y, t.y, w.y);
            proc(p.z, t.z, w.z); proc(p.w, t.w, w.w);
        }
    } else {
        for (int k = 0; k < full; ++k) {
            const int j = base + k * stride;
            float4 p = pred4[j]; int4 t = tgt4[j]; int4 w = lw4[j];
            proc(p.x, t.x, w.x); proc(p.y, t.y, w.y);
            proc(p.z, t.z, w.z); proc(p.w, t.w, w.w);
        }
    }
    {
        const int j = base + full * stride;
        if (j < n4) {
            float4 p = pred4[j]; int4 t = tgt4[j]; int4 w = lw4[j];
            proc(p.x, t.x, w.x); proc(p.y, t.y, w.y);
            proc(p.z, t.z, w.z); proc(p.w, t.w, w.w);
        }
    }
    if (blockIdx.x == 0 && tid < (n & 3)) {
        const float* predf = (const float*)pred4;
        const int*   tgtf  = (const int*)tgt4;
        const int*   lwf   = (const int*)lw4;
        const int j = n4 * 4 + tid;
        proc(predf[j], tgtf[j], lwf[j]);
    }

#pragma unroll
    for (int b = 0; b < BINS; ++b) {
#pragma unroll
        for (int off = 1; off <= 8; off <<= 1)
            A[b] += __shfl_xor(A[b], off, 64);
    }

    const int grp = tid >> 4;
    if ((tid & 15) == 0) {
#pragma unroll
        for (int b = 0; b < BINS; ++b) {
            float Cf = floorf(A[b] * (1.f / KPACK));
            red[b][grp]        = A[b] - KPACK * Cf;   // prefix S2 (log2 scale)
            red[BINS + b][grp] = Cf;                  // prefix count
        }
    }
    __syncthreads();
    if (tid < 2 * BINS) {
        float v = 0.f;
#pragma unroll
        for (int g = 0; g < 16; ++g) v += red[tid][g];
        part[blockIdx.x * (2 * BINS) + tid] = v;
    }
}

__global__ __launch_bounds__(FTPB) void ghmc_final_kernel(
    const float* __restrict__ part, float* __restrict__ out, int nb)
{
    float acc[2 * BINS];
#pragma unroll
    for (int v = 0; v < 2 * BINS; ++v) acc[v] = 0.f;

    const int tid = threadIdx.x;
    for (int i = tid; i < nb; i += FTPB) {
        const float4* rec = (const float4*)(part + (size_t)i * (2 * BINS));
        float4 a = rec[0], b = rec[1], c = rec[2], d = rec[3], e = rec[4];
        acc[0]  += a.x; acc[1]  += a.y; acc[2]  += a.z; acc[3]  += a.w;
        acc[4]  += b.x; acc[5]  += b.y; acc[6]  += b.z; acc[7]  += b.w;
        acc[8]  += c.x; acc[9]  += c.y; acc[10] += c.z; acc[11] += c.w;
        acc[12] += d.x; acc[13] += d.y; acc[14] += d.z; acc[15] += d.w;
        acc[16] += e.x; acc[17] += e.y; acc[18] += e.z; acc[19] += e.w;
    }

#pragma unroll
    for (int v = 0; v < 2 * BINS; ++v) {
#pragma unroll
        for (int off = 1; off <= 32; off <<= 1)
            acc[v] += __shfl_xor(acc[v], off, 64);
    }

    __shared__ float sh[2 * BINS][16];
    const int wv = tid >> 6, lane = tid & 63;
    if (lane == 0) {
#pragma unroll
        for (int v = 0; v < 2 * BINS; ++v) sh[v][wv] = acc[v];
    }
    __syncthreads();
    if (tid < 2 * BINS) {
        float s = 0.f;
#pragma unroll
        for (int g = 0; g < 16; ++g) s += sh[tid][g];
        sh[tid][0] = s;
    }
    __syncthreads();

    if (tid == 0) {
        float PS2[BINS + 1], PC[BINS + 1];
        PS2[BINS] = 0.f; PC[BINS] = 0.f;
#pragma unroll
        for (int b = 0; b < BINS; ++b) { PS2[b] = sh[b][0]; PC[b] = sh[BINS + b][0]; }

        float ti = PC[0];
        int nbn = 0;
        float cnts[BINS], sums[BINS];
#pragma unroll
        for (int b = 0; b < BINS; ++b) {
            cnts[b] = PC[b]  - PC[b + 1];
            sums[b] = PS2[b] - PS2[b + 1];
            nbn += (cnts[b] > 0.5f) ? 1 : 0;
        }
        float total = fmaxf(ti, 1.f);
        float nf    = (float)(nbn > 0 ? nbn : 1);
        float loss  = 0.f;
#pragma unroll
        for (int b = 0; b < BINS; ++b) {
            if (cnts[b] > 0.5f) {
                float w = (total / cnts[b]) / nf;
                loss += w * (sums[b] * LN2f);
            }
        }
        out[0] = loss / total * 1.0f;
    }
}

extern "C" void kernel_launch(void* const* d_in, const int* in_sizes, int n_in,
                              void* d_out, int out_size, void* d_ws, size_t ws_size,
                              hipStream_t stream)
{
    const float4* pred4 = (const float4*)d_in[0];
    const int4*   tgt4  = (const int4*)d_in[1];
    const int4*   lw4   = (const int4*)d_in[2];

    const int n  = in_sizes[0];
    const int n4 = n / 4;

    int nb = (n4 + TPB - 1) / TPB;
    if (nb > NB_MAX) nb = NB_MAX;
    int ws_cap = (int)(ws_size / (2 * BINS * sizeof(float)));
    if (nb > ws_cap) nb = ws_cap;
    if (nb < 1) nb = 1;

    float* part = (float*)d_ws;   // [nb][2*BINS]; probes scribble here first

    // ablation probes (outputs overwritten by the real hist kernel)
    probe_stream_x4<<<nb, TPB, 0, stream>>>(pred4, tgt4, lw4, part, n4);
    probe_proc_x4  <<<nb, TPB, 0, stream>>>(pred4, tgt4, lw4, part, n4);

    ghmc_hist_kernel<<<nb, TPB, 0, stream>>>(pred4, tgt4, lw4, part, n4, n);
    ghmc_final_kernel<<<1, FTPB, 0, stream>>>(part, (float*)d_out, nb);
}

// Round 14
// 35.052 us; speedup vs baseline: 5.4329x; 5.4329x over previous
//
#include <hip/hip_runtime.h>

#define BINS 10
#define TPB  256
#define NB_MAX 2048
#define FTPB 1024   // finalize block size
#define KPACK 16384.0f
#define LN2f   0.69314718055994531f
#define LOG2Ef 1.44269504088896f

// Pass 1 (round 14): EXACT probe_proc structure -- the R13 ablation showed
// the naive guarded grid-stride loop (register loads, direct consumption)
// runs a cold pass in ~22 us while every hand-pipelined variant (rotation,
// LDS queue, asm vmcnt waits) took 41-54 us. The compiler + 23-wave TLP
// schedule this better than any explicit pipeline; read-MLP caps the
// pattern at ~2.7 TB/s.
// Math: threshold-prefix binning (bin = sum_k (q >= logit(k/10)), no
// sigmoid/rcp) with (count,sum) fused via +KPACK per element; native
// exp2/log transcendentals; prefix un-diffed in the finalize kernel.
__global__ __launch_bounds__(TPB, 4) void ghmc_hist_kernel(
    const float4* __restrict__ pred4,
    const int4*   __restrict__ tgt4,
    const int4*   __restrict__ lw4,
    float* __restrict__ part,      // [nb][2*BINS]
    int n4, int n)
{
    float A[BINS];
#pragma unroll
    for (int b = 0; b < BINS; ++b) A[b] = 0.f;

    const float Q[9] = {-2.19722458f, -1.38629436f, -0.84729786f,
                        -0.40546511f,  0.0f,         0.40546511f,
                         0.84729786f,  1.38629436f,  2.19722458f};

    auto proc = [&](float p, int t, int w) {
        // q = t ? -p : p;  bin from thresholds on q;  bce = softplus(q)
        float q    = __int_as_float(__float_as_int(p) ^ (int)((unsigned)t << 31));
        float e    = __builtin_amdgcn_exp2f(fabsf(q) * -LOG2Ef);   // e^-|q|
        float d    = 1.f + e;
        float bce2 = fmaf(fmaxf(q, 0.f), LOG2Ef,
                          __builtin_amdgcn_logf(d));               // softplus/ln2
        float v    = (w > 0) ? (bce2 + KPACK) : 0.f;
        A[0] += v;
#pragma unroll
        for (int k = 0; k < 9; ++k)
            A[k + 1] += (q >= Q[k]) ? v : 0.f;   // bin >= k+1  <=>  q >= Q[k]
    };

    const int tid    = threadIdx.x;
    const int stride = gridDim.x * TPB;
    const int base   = blockIdx.x * TPB + tid;
    const int full   = n4 / stride;

    // naive guarded loop, one extra iteration covers the remainder quad
    for (int k = 0; k <= full; ++k) {
        const int i = base + k * stride;
        if (i < n4) {
            float4 p = pred4[i];
            int4   t = tgt4[i];
            int4   w = lw4[i];
            proc(p.x, t.x, w.x); proc(p.y, t.y, w.y);
            proc(p.z, t.z, w.z); proc(p.w, t.w, w.w);
        }
    }
    // scalar tail (n not divisible by 4; cold at bench shape)
    if (blockIdx.x == 0 && tid < (n & 3)) {
        const float* predf = (const float*)pred4;
        const int*   tgtf  = (const int*)tgt4;
        const int*   lwf   = (const int*)lw4;
        const int j = n4 * 4 + tid;
        proc(predf[j], tgtf[j], lwf[j]);
    }

    // 4-level xor reduce of the 10 fused prefix accumulators
    // (16-lane group total <= 16*20*16407 ~ 5.3M < 2^24: count part exact)
#pragma unroll
    for (int b = 0; b < BINS; ++b) {
#pragma unroll
        for (int off = 1; off <= 8; off <<= 1)
            A[b] += __shfl_xor(A[b], off, 64);
    }

    // 16 group leaders separate prefix count / prefix sum; 20 threads write
    __shared__ float red[2 * BINS][16];   // 1.28 KB
    const int grp = tid >> 4;
    if ((tid & 15) == 0) {
#pragma unroll
        for (int b = 0; b < BINS; ++b) {
            float Cf = floorf(A[b] * (1.f / KPACK));
            red[b][grp]        = A[b] - KPACK * Cf;   // prefix S2 (log2 scale)
            red[BINS + b][grp] = Cf;                  // prefix count
        }
    }
    __syncthreads();
    if (tid < 2 * BINS) {
        float v = 0.f;
#pragma unroll
        for (int g = 0; g < 16; ++g) v += red[tid][g];
        part[blockIdx.x * (2 * BINS) + tid] = v;   // contiguous record
    }
}

// Pass 2: reduce nb 20-float records (rows 0..9 prefix-S2, 10..19 prefix-C),
// un-diff the prefixes, compute the scalar loss (S = S2 * ln2).
__global__ __launch_bounds__(FTPB) void ghmc_final_kernel(
    const float* __restrict__ part, float* __restrict__ out, int nb)
{
    float acc[2 * BINS];
#pragma unroll
    for (int v = 0; v < 2 * BINS; ++v) acc[v] = 0.f;

    const int tid = threadIdx.x;
    for (int i = tid; i < nb; i += FTPB) {
        const float4* rec = (const float4*)(part + (size_t)i * (2 * BINS));
        float4 a = rec[0], b = rec[1], c = rec[2], d = rec[3], e = rec[4];
        acc[0]  += a.x; acc[1]  += a.y; acc[2]  += a.z; acc[3]  += a.w;
        acc[4]  += b.x; acc[5]  += b.y; acc[6]  += b.z; acc[7]  += b.w;
        acc[8]  += c.x; acc[9]  += c.y; acc[10] += c.z; acc[11] += c.w;
        acc[12] += d.x; acc[13] += d.y; acc[14] += d.z; acc[15] += d.w;
        acc[16] += e.x; acc[17] += e.y; acc[18] += e.z; acc[19] += e.w;
    }

#pragma unroll
    for (int v = 0; v < 2 * BINS; ++v) {
#pragma unroll
        for (int off = 1; off <= 32; off <<= 1)
            acc[v] += __shfl_xor(acc[v], off, 64);
    }

    __shared__ float sh[2 * BINS][16];
    const int wv = tid >> 6, lane = tid & 63;
    if (lane == 0) {
#pragma unroll
        for (int v = 0; v < 2 * BINS; ++v) sh[v][wv] = acc[v];
    }
    __syncthreads();
    if (tid < 2 * BINS) {
        float s = 0.f;
#pragma unroll
        for (int g = 0; g < 16; ++g) s += sh[tid][g];
        sh[tid][0] = s;
    }
    __syncthreads();

    if (tid == 0) {
        float PS2[BINS + 1], PC[BINS + 1];
        PS2[BINS] = 0.f; PC[BINS] = 0.f;
#pragma unroll
        for (int b = 0; b < BINS; ++b) { PS2[b] = sh[b][0]; PC[b] = sh[BINS + b][0]; }

        float ti = PC[0];          // total valid = prefix count at level 0
        int nbn = 0;
        float cnts[BINS], sums[BINS];
#pragma unroll
        for (int b = 0; b < BINS; ++b) {
            cnts[b] = PC[b]  - PC[b + 1];    // exact integer diff
            sums[b] = PS2[b] - PS2[b + 1];
            nbn += (cnts[b] > 0.5f) ? 1 : 0;
        }
        float total = fmaxf(ti, 1.f);
        float nf    = (float)(nbn > 0 ? nbn : 1);
        float loss  = 0.f;
#pragma unroll
        for (int b = 0; b < BINS; ++b) {
            if (cnts[b] > 0.5f) {
                float w = (total / cnts[b]) / nf;     // w_bin[b]
                loss += w * (sums[b] * LN2f);         // S = S2 * ln2
            }
        }
        out[0] = loss / total * 1.0f;  // LOSS_WEIGHT = 1.0
    }
}

extern "C" void kernel_launch(void* const* d_in, const int* in_sizes, int n_in,
                              void* d_out, int out_size, void* d_ws, size_t ws_size,
                              hipStream_t stream)
{
    const float4* pred4 = (const float4*)d_in[0];
    const int4*   tgt4  = (const int4*)d_in[1];
    const int4*   lw4   = (const int4*)d_in[2];

    const int n  = in_sizes[0];
    const int n4 = n / 4;

    int nb = (n4 + TPB - 1) / TPB;
    if (nb > NB_MAX) nb = NB_MAX;
    int ws_cap = (int)(ws_size / (2 * BINS * sizeof(float)));
    if (nb > ws_cap) nb = ws_cap;
    if (nb < 1) nb = 1;

    float* part = (float*)d_ws;   // [nb][2*BINS]

    ghmc_hist_kernel<<<nb, TPB, 0, stream>>>(pred4, tgt4, lw4, part, n4, n);
    ghmc_final_kernel<<<1, FTPB, 0, stream>>>(part, (float*)d_out, nb);
}